// Round 3
// baseline (1033.644 us; speedup 1.0000x reference)
//
#include <hip/hip_runtime.h>
#include <hip/hip_bf16.h>
#include <stdint.h>

// Problem dims (fixed by reference): B=64, T=512, H=1024, A=300
#define B_DIM 64
#define T_DIM 512
#define H_DIM 1024
#define K_DIM 1024
#define M_DIM (B_DIM * T_DIM)  // 32768 rows of the big GEMM
#define GM_BK 64
#define IG 4
#define NBLK 512                // persistent grid: 2 blocks/CU x 256 CU
#define NTHR (NBLK * 256)       // 131072 threads

typedef __bf16 bf16x8 __attribute__((ext_vector_type(8)));
typedef float f32x4 __attribute__((ext_vector_type(4)));

__device__ __forceinline__ float tanh_fast(float x) {
  float e = __expf(2.0f * x);
  return 1.0f - 2.0f / (e + 1.0f);
}

__device__ __forceinline__ float bf2f(unsigned short u) {
  return __uint_as_float(((unsigned int)u) << 16);
}

// async global->LDS, 16B per lane. LDS dest must be wave-uniform base + lane*16.
__device__ __forceinline__ void async_cp16(const void* gp, void* lp) {
  __builtin_amdgcn_global_load_lds(
      reinterpret_cast<const __attribute__((address_space(1))) uint32_t*>(
          reinterpret_cast<uintptr_t>(gp)),
      reinterpret_cast<__attribute__((address_space(3))) uint32_t*>(
          reinterpret_cast<uintptr_t>(lp)),
      16, 0, 0);
}

__device__ __forceinline__ void cvt4(const float4& v, uint2* dst) {
  union { __bf16 b[4]; uint2 u; } o;
  o.b[0] = (__bf16)v.x; o.b[1] = (__bf16)v.y; o.b[2] = (__bf16)v.z; o.b[3] = (__bf16)v.w;
  *dst = o.u;
}

// Hand-rolled grid barrier: device-scope atomics + fences (G16-sanctioned path;
// atomicAdd on global is device-scope, m20). All NBLK blocks are co-resident by
// construction (launch_bounds(256,2) => VGPR<=256 => >=2 blocks/CU; LDS 48KB =>
// 3 blocks/CU; NBLK = 2*256). Bounded spin escape: if the residency reasoning
// were ever wrong we produce a wrong answer, not a hung container.
__device__ __forceinline__ void grid_barrier(unsigned* cnt, int k) {
  __syncthreads();
  if (threadIdx.x == 0) {
    __threadfence();  // release my writes (flush to device-visible point)
    __hip_atomic_fetch_add(&cnt[k], 1u, __ATOMIC_RELEASE, __HIP_MEMORY_SCOPE_AGENT);
    unsigned spins = 0;
    while (__hip_atomic_load(&cnt[k], __ATOMIC_ACQUIRE, __HIP_MEMORY_SCOPE_AGENT) <
           (unsigned)NBLK) {
      __builtin_amdgcn_s_sleep(8);
      if (++spins > (1u << 20)) break;  // ~200ms escape hatch, never trips live
    }
    __threadfence();  // acquire others' writes
  }
  __syncthreads();
}

// LDS re-used across phases (phases separated by grid barrier incl. block sync)
union SharedU {
  struct { __bf16 lA[256 * GM_BK]; __bf16 lB[128 * GM_BK]; } g;  // 48 KB gemm
  struct { float al[64]; float red[8]; } w;                      // wsum
  float sv[IG][H_DIM];                                           // 16 KB rowvec
};

// ============================ persistent mega-kernel ============================
// Phase bodies are verbatim from the verified 5-kernel pipeline (R1, 344us);
// only grid-stride index math and the barrier scaffolding are new.
__global__ __launch_bounds__(256, 2) void mega_kernel(
    const float* __restrict__ hidden, __bf16* __restrict__ hidBf,
    const float* __restrict__ W_h, __bf16* __restrict__ whBf,
    float* __restrict__ scores, const float* __restrict__ b_h,
    const float* __restrict__ w_w, float* __restrict__ r8,
    const float* __restrict__ W_p, const float* __restrict__ b_p,
    const float* __restrict__ W_x, const float* __restrict__ b_x,
    float* __restrict__ rp, float* __restrict__ xq, float* __restrict__ out,
    unsigned* __restrict__ barcnt) {
  __shared__ __attribute__((aligned(16))) SharedU sh;
  const int tid = threadIdx.x;
  const int bid = blockIdx.x;
  const int gt = bid * 256 + tid;  // 0..131071

  // ---------------- phase 1: cvt hidden + cvt W_h + zero scores ----------------
  {
    const float4* hs = reinterpret_cast<const float4*>(hidden);
    uint2* hd = reinterpret_cast<uint2*>(hidBf);
#pragma unroll 4
    for (int it = 0; it < 64; ++it) {  // 8388608 float4 = 64 * NTHR
      int i = it * NTHR + gt;
      float4 v = hs[i];
      cvt4(v, &hd[i]);
    }
    const float4* wsrc = reinterpret_cast<const float4*>(W_h);
    uint2* wd = reinterpret_cast<uint2*>(whBf);
#pragma unroll
    for (int it = 0; it < 2; ++it) {   // 262144 float4 = 2 * NTHR
      int i = it * NTHR + gt;
      float4 v = wsrc[i];
      cvt4(v, &wd[i]);
    }
    if (gt < 8192) reinterpret_cast<float4*>(scores)[gt] = make_float4(0.f, 0.f, 0.f, 0.f);
  }
  grid_barrier(barcnt, 0);

  // ---------------- phase 2: fused GEMM + tanh + dot(w_w) -> scores ----------------
  // 1024 tiles (128m x 8n), 2 per block: tt = bid, bid+512. Same m-panel both
  // passes (A L2-reuse), n-panels 0-3 then 4-7. XCD swizzle: m = tt&127.
  {
    const int wv = tid >> 6;
    const int lane = tid & 63;
    const int wm = wv & 1, wn = wv >> 1;           // waves: 2m x 2n, each 128x64
    const int r16 = lane & 15, quad = lane >> 4;
    const int sw = r16 >> 1;

    __bf16* lAd[8]; int rowA[8], kcA[8];
#pragma unroll
    for (int j = 0; j < 8; ++j) {
      int c = j * 256 + tid;
      rowA[j] = c >> 3;
      kcA[j] = (c & 7) ^ ((rowA[j] >> 1) & 7);
      lAd[j] = &sh.g.lA[c * 8];
    }
    __bf16* lBd[4]; int rowB[4], kcB[4];
#pragma unroll
    for (int j = 0; j < 4; ++j) {
      int c = j * 256 + tid;
      rowB[j] = c >> 3;
      kcB[j] = (c & 7) ^ ((rowB[j] >> 1) & 7);
      lBd[j] = &sh.g.lB[c * 8];
    }
    const __bf16* pa[2]; const __bf16* pb[2];
#pragma unroll
    for (int kk = 0; kk < 2; ++kk) {
      pa[kk] = &sh.g.lA[(wm * 128 + r16) * GM_BK + ((kk * 4 + quad) ^ sw) * 8];
      pb[kk] = &sh.g.lB[(wn * 64 + r16) * GM_BK + ((kk * 4 + quad) ^ sw) * 8];
    }

#pragma unroll 1
    for (int tpass = 0; tpass < 2; ++tpass) {
      const int tt = bid + tpass * NBLK;
      const int m0 = (tt & 127) * 256;
      const int n0 = (tt >> 7) * 128;

      const __bf16* gA[8];
#pragma unroll
      for (int j = 0; j < 8; ++j) gA[j] = hidBf + (size_t)(m0 + rowA[j]) * K_DIM + kcA[j] * 8;
      const __bf16* gB[4];
#pragma unroll
      for (int j = 0; j < 4; ++j) gB[j] = whBf + (size_t)(n0 + rowB[j]) * K_DIM + kcB[j] * 8;

      f32x4 acc[8][4] = {};

#pragma unroll
      for (int k0 = 0; k0 < K_DIM; k0 += GM_BK) {
#pragma unroll
        for (int j = 0; j < 8; ++j) async_cp16(gA[j] + k0, lAd[j]);
#pragma unroll
        for (int j = 0; j < 4; ++j) async_cp16(gB[j] + k0, lBd[j]);
        __syncthreads();
#pragma unroll
        for (int kk = 0; kk < 2; ++kk) {
          bf16x8 bfr[4];
#pragma unroll
          for (int ni = 0; ni < 4; ++ni)
            bfr[ni] = *reinterpret_cast<const bf16x8*>(pb[kk] + ni * 16 * GM_BK);
          bf16x8 af[8];
#pragma unroll
          for (int mi = 0; mi < 8; ++mi)
            af[mi] = *reinterpret_cast<const bf16x8*>(pa[kk] + mi * 16 * GM_BK);
#pragma unroll
          for (int mi = 0; mi < 8; ++mi)
#pragma unroll
            for (int ni = 0; ni < 4; ++ni)
              acc[mi][ni] = __builtin_amdgcn_mfma_f32_16x16x32_bf16(af[mi], bfr[ni], acc[mi][ni], 0, 0, 0);
        }
        __syncthreads();
      }

      // epilogue: C/D layout col=lane&15, row=quad*4+reg (m89-verified).
      // Reads only registers/global -> no LDS hazard vs next pass's staging.
      float bhv[4], wwv[4];
#pragma unroll
      for (int ni = 0; ni < 4; ++ni) {
        int n = n0 + wn * 64 + ni * 16 + r16;
        bhv[ni] = b_h[n];
        wwv[ni] = w_w[n];
      }
#pragma unroll
      for (int mi = 0; mi < 8; ++mi) {
#pragma unroll
        for (int rg = 0; rg < 4; ++rg) {
          float s = 0.f;
#pragma unroll
          for (int ni = 0; ni < 4; ++ni)
            s += tanh_fast(acc[mi][ni][rg] + bhv[ni]) * wwv[ni];
          s += __shfl_xor(s, 1, 16);
          s += __shfl_xor(s, 2, 16);
          s += __shfl_xor(s, 4, 16);
          s += __shfl_xor(s, 8, 16);
          if (r16 == 0) {
            int m = m0 + wm * 128 + mi * 16 + quad * 4 + rg;
            atomicAdd(&scores[m], s);
          }
        }
      }
    }
  }
  grid_barrier(barcnt, 1);

  // ------- phase 3: softmax (recomputed per block) + weighted-sum partials -------
  // NOTE: r8 aliases whBf bytes; whBf is dead after phase 2 (barrier above).
  {
    const int b = bid >> 3, tc = bid & 7;
    const int wv = tid >> 6, lane = tid & 63;
    float v0 = scores[b * T_DIM + tid];
    float v1 = scores[b * T_DIM + 256 + tid];
    float mx = fmaxf(v0, v1);
#pragma unroll
    for (int off = 1; off < 64; off <<= 1) mx = fmaxf(mx, __shfl_xor(mx, off, 64));
    if (lane == 0) sh.w.red[wv] = mx;
    __syncthreads();
    mx = fmaxf(fmaxf(sh.w.red[0], sh.w.red[1]), fmaxf(sh.w.red[2], sh.w.red[3]));
    float e0 = __expf(v0 - mx), e1 = __expf(v1 - mx);
    float s = e0 + e1;
#pragma unroll
    for (int off = 1; off < 64; off <<= 1) s += __shfl_xor(s, off, 64);
    if (lane == 0) sh.w.red[4 + wv] = s;
    __syncthreads();
    float inv = 1.0f / (sh.w.red[4] + sh.w.red[5] + sh.w.red[6] + sh.w.red[7]);
    if (tid < 64) sh.w.al[tid] = __expf(scores[b * T_DIM + tc * 64 + tid] - mx) * inv;
    __syncthreads();
    const __bf16* hp = hidBf + (size_t)b * T_DIM * H_DIM + (size_t)tc * 64 * H_DIM + tid * 4;
    float4 acc = make_float4(0.f, 0.f, 0.f, 0.f);
#pragma unroll 8
    for (int t = 0; t < 64; ++t) {
      float a = sh.w.al[t];
      ushort4 u = *reinterpret_cast<const ushort4*>(hp + (size_t)t * H_DIM);
      acc.x += a * bf2f(u.x);
      acc.y += a * bf2f(u.y);
      acc.z += a * bf2f(u.z);
      acc.w += a * bf2f(u.w);
    }
    *reinterpret_cast<float4*>(r8 + (size_t)(b * 8 + tc) * H_DIM + tid * 4) = acc;
  }
  grid_barrier(barcnt, 2);

  // ---- phase 4: rp = (sum_tc r8) @ W_p^T + b_p ; xq = hidden[:,-1,:] @ W_x^T + b_x ----
  {
    const int h0 = (bid & 15) * 64;
    const int i0 = ((bid >> 4) & 15) * IG;
    const int which = bid >> 8;
    const float* W = which ? W_x : W_p;
    const float* bias = which ? b_x : b_p;
    float* dst = which ? xq : rp;
    if (which == 0) {
#pragma unroll
      for (int ii = 0; ii < IG; ++ii) {
        const float* src = r8 + (size_t)(i0 + ii) * 8 * H_DIM + tid * 4;
        float4 a = *reinterpret_cast<const float4*>(src);
#pragma unroll
        for (int tc = 1; tc < 8; ++tc) {
          float4 v = *reinterpret_cast<const float4*>(src + (size_t)tc * H_DIM);
          a.x += v.x; a.y += v.y; a.z += v.z; a.w += v.w;
        }
        *reinterpret_cast<float4*>(&sh.sv[ii][tid * 4]) = a;
      }
    } else {
#pragma unroll
      for (int ii = 0; ii < IG; ++ii) {
        const float* src = hidden + (size_t)(i0 + ii) * T_DIM * H_DIM +
                           (size_t)(T_DIM - 1) * H_DIM + tid * 4;
        *reinterpret_cast<float4*>(&sh.sv[ii][tid * 4]) = *reinterpret_cast<const float4*>(src);
      }
    }
    __syncthreads();
    const int hl = tid >> 2;        // output row within block: 0..63
    const int kq = tid & 3;         // 4 lanes split K, contiguous 64B per group
    const float* wr = W + (size_t)(h0 + hl) * H_DIM + kq * 4;
    float acc[IG] = {};
#pragma unroll 8
    for (int j = 0; j < 64; ++j) {
      float4 w4 = *reinterpret_cast<const float4*>(wr + j * 16);
#pragma unroll
      for (int ii = 0; ii < IG; ++ii) {
        float4 s4 = *reinterpret_cast<const float4*>(&sh.sv[ii][kq * 4 + j * 16]);
        acc[ii] += w4.x * s4.x + w4.y * s4.y + w4.z * s4.z + w4.w * s4.w;
      }
    }
#pragma unroll
    for (int ii = 0; ii < IG; ++ii) {
      acc[ii] += __shfl_xor(acc[ii], 1, 4);
      acc[ii] += __shfl_xor(acc[ii], 2, 4);
    }
    if (kq == 0) {
      float bb = bias[h0 + hl];
#pragma unroll
      for (int ii = 0; ii < IG; ++ii)
        dst[(size_t)(i0 + ii) * H_DIM + h0 + hl] = acc[ii] + bb;
    }
  }
  grid_barrier(barcnt, 3);

  // ---------------- phase 5: out[i,j,h] = tanh(rp[i,h] + xq[j,h]) ----------------
  {
#pragma unroll
    for (int it = 0; it < 8; ++it) {  // 1048576 float4 = 8 * NTHR
      int idx = it * NTHR + gt;
      int e = idx * 4;
      int i = e >> 16;
      int j = (e >> 10) & 63;
      int h = e & 1023;
      float4 a = *reinterpret_cast<const float4*>(&rp[i * H_DIM + h]);
      float4 b = *reinterpret_cast<const float4*>(&xq[j * H_DIM + h]);
      float4 o;
      o.x = tanh_fast(a.x + b.x);
      o.y = tanh_fast(a.y + b.y);
      o.z = tanh_fast(a.z + b.z);
      o.w = tanh_fast(a.w + b.w);
      *reinterpret_cast<float4*>(&out[e]) = o;
    }
  }
}

extern "C" void kernel_launch(void* const* d_in, const int* in_sizes, int n_in,
                              void* d_out, int out_size, void* d_ws, size_t ws_size,
                              hipStream_t stream) {
  const float* hidden = (const float*)d_in[0];
  // aspect (1), W_v (4), b_v (5), w_b (7) cancel under softmax -> unused
  const float* W_h = (const float*)d_in[2];
  const float* b_h = (const float*)d_in[3];
  const float* w_w = (const float*)d_in[6];  // use first H entries
  const float* W_p = (const float*)d_in[8];
  const float* b_p = (const float*)d_in[9];
  const float* W_x = (const float*)d_in[10];
  const float* b_x = (const float*)d_in[11];
  float* out = (float*)d_out;

  char* ws = (char*)d_ws;
  __bf16* hidBf = (__bf16*)ws;                  // 64 MB  [0, 67108864)
  __bf16* whBf = (__bf16*)(ws + 67108864);      // 2 MB   [67108864, 69206016)
  float* r8 = (float*)(ws + 67108864);          // 2 MB, ALIASES whBf (whBf dead
                                                // after phase 2; r8 written phase 3)
  float* scores = (float*)(ws + 69206016);      // 128 KB [69206016, 69337088)
  float* rpB = (float*)(ws + 69337088);         // 256 KB
  float* xqB = (float*)(ws + 69599232);         // 256 KB (ends 69861376)
  unsigned* barcnt = (unsigned*)(ws + 69861376);// 64 B barrier counters

  // zero the barrier counters each launch (capturable; the test's own reset
  // uses hipMemsetAsync)
  hipMemsetAsync(barcnt, 0, 64, stream);

  mega_kernel<<<NBLK, 256, 0, stream>>>(hidden, hidBf, W_h, whBf, scores, b_h,
                                        w_w, r8, W_p, b_p, W_x, b_x, rpB, xqB,
                                        out, barcnt);
}

// Round 4
// 358.596 us; speedup vs baseline: 2.8825x; 2.8825x over previous
//
#include <hip/hip_runtime.h>
#include <hip/hip_bf16.h>
#include <stdint.h>

// Problem dims (fixed by reference): B=64, T=512, H=1024, A=300
#define B_DIM 64
#define T_DIM 512
#define H_DIM 1024
#define K_DIM 1024
#define M_DIM (B_DIM * T_DIM)  // 32768 rows of the big GEMM
#define GM_BK 64
#define IG 4

typedef __bf16 bf16x8 __attribute__((ext_vector_type(8)));
typedef float f32x4 __attribute__((ext_vector_type(4)));

__device__ __forceinline__ float tanh_fast(float x) {
  float e = __expf(2.0f * x);
  return 1.0f - 2.0f / (e + 1.0f);
}

__device__ __forceinline__ float bf2f(unsigned short u) {
  return __uint_as_float(((unsigned int)u) << 16);
}

// async global->LDS, 16B per lane. LDS dest must be wave-uniform base + lane*16.
__device__ __forceinline__ void async_cp16(const void* gp, void* lp) {
  __builtin_amdgcn_global_load_lds(
      reinterpret_cast<const __attribute__((address_space(1))) uint32_t*>(
          reinterpret_cast<uintptr_t>(gp)),
      reinterpret_cast<__attribute__((address_space(3))) uint32_t*>(
          reinterpret_cast<uintptr_t>(lp)),
      16, 0, 0);
}

__device__ __forceinline__ void cvt4(const float4& v, uint2* dst) {
  union { __bf16 b[4]; uint2 u; } o;
  o.b[0] = (__bf16)v.x; o.b[1] = (__bf16)v.y; o.b[2] = (__bf16)v.z; o.b[3] = (__bf16)v.w;
  *dst = o.u;
}

// ---- prep: cvt hidden (32768 blk) + cvt W_h (1024 blk) + zero scores (32 blk) ----
__global__ void prep_kernel(const float* __restrict__ hidden, __bf16* __restrict__ hidBf,
                            const float* __restrict__ Wh, __bf16* __restrict__ whBf,
                            float* __restrict__ scores) {
  const int bid = blockIdx.x, tid = threadIdx.x;
  if (bid < 32768) {
    int i = bid * 256 + tid;
    float4 v = reinterpret_cast<const float4*>(hidden)[i];
    cvt4(v, &reinterpret_cast<uint2*>(hidBf)[i]);
  } else if (bid < 33792) {
    int i = (bid - 32768) * 256 + tid;
    float4 v = reinterpret_cast<const float4*>(Wh)[i];
    cvt4(v, &reinterpret_cast<uint2*>(whBf)[i]);
  } else {
    int i = (bid - 33792) * 256 + tid;
    reinterpret_cast<float4*>(scores)[i] = make_float4(0.f, 0.f, 0.f, 0.f);
  }
}

// ---------------- fused GEMM + tanh + dot(w_w) -> scores (verified, 85us) ----
// Block tile 256Mx128N, 4 waves each 128x64 (8x4 acc). LDS A 32KB + B 16KB,
// XOR-swizzled (conflicts=0 verified). Full K unroll folds global offsets into
// the global_load_lds imm. XCD swizzle m=bid&127. UNTOUCHED from the 344us run.
__global__ __launch_bounds__(256, 2) void gemm_scores_kernel(
    const __bf16* __restrict__ A, const __bf16* __restrict__ Bm,
    const float* __restrict__ bh, const float* __restrict__ ww,
    float* __restrict__ scores) {
  __shared__ __attribute__((aligned(16))) __bf16 lA[256 * GM_BK];
  __shared__ __attribute__((aligned(16))) __bf16 lB[128 * GM_BK];
  const int tid = threadIdx.x;
  const int bid = blockIdx.x;
  const int m0 = (bid & 127) * 256;
  const int n0 = (bid >> 7) * 128;
  const int wv = tid >> 6;
  const int lane = tid & 63;
  const int wm = wv & 1, wn = wv >> 1;
  const int r16 = lane & 15, quad = lane >> 4;
  f32x4 acc[8][4] = {};
  const __bf16* gA[8]; __bf16* lAd[8];
#pragma unroll
  for (int j = 0; j < 8; ++j) {
    int c = j * 256 + tid;
    int row = c >> 3;
    int p = c & 7;
    int kc = p ^ ((row >> 1) & 7);
    gA[j] = A + (size_t)(m0 + row) * K_DIM + kc * 8;
    lAd[j] = &lA[c * 8];
  }
  const __bf16* gB[4]; __bf16* lBd[4];
#pragma unroll
  for (int j = 0; j < 4; ++j) {
    int c = j * 256 + tid;
    int row = c >> 3;
    int p = c & 7;
    int kc = p ^ ((row >> 1) & 7);
    gB[j] = Bm + (size_t)(n0 + row) * K_DIM + kc * 8;
    lBd[j] = &lB[c * 8];
  }
  const int sw = r16 >> 1;
  const __bf16* pa[2]; const __bf16* pb[2];
#pragma unroll
  for (int kk = 0; kk < 2; ++kk) {
    pa[kk] = &lA[(wm * 128 + r16) * GM_BK + ((kk * 4 + quad) ^ sw) * 8];
    pb[kk] = &lB[(wn * 64 + r16) * GM_BK + ((kk * 4 + quad) ^ sw) * 8];
  }
#pragma unroll
  for (int k0 = 0; k0 < K_DIM; k0 += GM_BK) {
#pragma unroll
    for (int j = 0; j < 8; ++j) async_cp16(gA[j] + k0, lAd[j]);
#pragma unroll
    for (int j = 0; j < 4; ++j) async_cp16(gB[j] + k0, lBd[j]);
    __syncthreads();
#pragma unroll
    for (int kk = 0; kk < 2; ++kk) {
      bf16x8 bfr[4];
#pragma unroll
      for (int ni = 0; ni < 4; ++ni)
        bfr[ni] = *reinterpret_cast<const bf16x8*>(pb[kk] + ni * 16 * GM_BK);
      bf16x8 af[8];
#pragma unroll
      for (int mi = 0; mi < 8; ++mi)
        af[mi] = *reinterpret_cast<const bf16x8*>(pa[kk] + mi * 16 * GM_BK);
#pragma unroll
      for (int mi = 0; mi < 8; ++mi)
#pragma unroll
        for (int ni = 0; ni < 4; ++ni)
          acc[mi][ni] = __builtin_amdgcn_mfma_f32_16x16x32_bf16(af[mi], bfr[ni], acc[mi][ni], 0, 0, 0);
    }
    __syncthreads();
  }
  float bhv[4], wwv[4];
#pragma unroll
  for (int ni = 0; ni < 4; ++ni) {
    int n = n0 + wn * 64 + ni * 16 + r16;
    bhv[ni] = bh[n];
    wwv[ni] = ww[n];
  }
#pragma unroll
  for (int mi = 0; mi < 8; ++mi) {
#pragma unroll
    for (int rg = 0; rg < 4; ++rg) {
      float s = 0.f;
#pragma unroll
      for (int ni = 0; ni < 4; ++ni)
        s += tanh_fast(acc[mi][ni][rg] + bhv[ni]) * wwv[ni];
      s += __shfl_xor(s, 1, 16);
      s += __shfl_xor(s, 2, 16);
      s += __shfl_xor(s, 4, 16);
      s += __shfl_xor(s, 8, 16);
      if (r16 == 0) {
        int m = m0 + wm * 128 + mi * 16 + quad * 4 + rg;
        atomicAdd(&scores[m], s);
      }
    }
  }
}

// ------- wsum v2: full-occupancy softmax + weighted-sum partials (2048 blocks) -------
// R3's mega run measured the occupancy cliff: streaming phases at 2 blocks/CU run
// ~4x under speed. Old wsum was 512 blocks = 2/CU. Now 2048 blocks (8/CU, 32
// waves/CU): block (b = bid>>5, tc = bid&31) handles 16 t-rows, writes partial
// to r32[b][tc][H]. Softmax recompute per block is 2KB of L2-resident reads.
__global__ void wsum32_kernel(const float* __restrict__ scores,
                              const __bf16* __restrict__ hiddenBf,
                              float* __restrict__ r32) {
  __shared__ float al[16];
  __shared__ float red[8];
  const int bid = blockIdx.x, tid = threadIdx.x;
  const int b = bid >> 5, tc = bid & 31;
  const int wv = tid >> 6, lane = tid & 63;
  float v0 = scores[b * T_DIM + tid];
  float v1 = scores[b * T_DIM + 256 + tid];
  float mx = fmaxf(v0, v1);
#pragma unroll
  for (int off = 1; off < 64; off <<= 1) mx = fmaxf(mx, __shfl_xor(mx, off, 64));
  if (lane == 0) red[wv] = mx;
  __syncthreads();
  mx = fmaxf(fmaxf(red[0], red[1]), fmaxf(red[2], red[3]));
  float e0 = __expf(v0 - mx), e1 = __expf(v1 - mx);
  float s = e0 + e1;
#pragma unroll
  for (int off = 1; off < 64; off <<= 1) s += __shfl_xor(s, off, 64);
  if (lane == 0) red[4 + wv] = s;
  __syncthreads();
  float inv = 1.0f / (red[4] + red[5] + red[6] + red[7]);
  if (tid < 16) al[tid] = __expf(scores[b * T_DIM + tc * 16 + tid] - mx) * inv;
  __syncthreads();
  const __bf16* hp = hiddenBf + (size_t)b * T_DIM * H_DIM + (size_t)tc * 16 * H_DIM + tid * 4;
  float4 acc = make_float4(0.f, 0.f, 0.f, 0.f);
#pragma unroll
  for (int t = 0; t < 16; ++t) {
    float a = al[t];
    ushort4 u = *reinterpret_cast<const ushort4*>(hp + (size_t)t * H_DIM);
    acc.x += a * bf2f(u.x);
    acc.y += a * bf2f(u.y);
    acc.z += a * bf2f(u.z);
    acc.w += a * bf2f(u.w);
  }
  *reinterpret_cast<float4*>(r32 + (size_t)(b * 32 + tc) * H_DIM + tid * 4) = acc;
}

// ------- legacy wsum (8 partials, verified in the 344us run) — ws_size fallback -------
__global__ void wsum_kernel(const float* __restrict__ scores,
                            const __bf16* __restrict__ hiddenBf,
                            float* __restrict__ r8) {
  __shared__ float al[64];
  __shared__ float red[8];
  const int bid = blockIdx.x, tid = threadIdx.x;
  const int b = bid >> 3, tc = bid & 7;
  const int wv = tid >> 6, lane = tid & 63;
  float v0 = scores[b * T_DIM + tid];
  float v1 = scores[b * T_DIM + 256 + tid];
  float mx = fmaxf(v0, v1);
#pragma unroll
  for (int off = 1; off < 64; off <<= 1) mx = fmaxf(mx, __shfl_xor(mx, off, 64));
  if (lane == 0) red[wv] = mx;
  __syncthreads();
  mx = fmaxf(fmaxf(red[0], red[1]), fmaxf(red[2], red[3]));
  float e0 = __expf(v0 - mx), e1 = __expf(v1 - mx);
  float s = e0 + e1;
#pragma unroll
  for (int off = 1; off < 64; off <<= 1) s += __shfl_xor(s, off, 64);
  if (lane == 0) red[4 + wv] = s;
  __syncthreads();
  float inv = 1.0f / (red[4] + red[5] + red[6] + red[7]);
  if (tid < 64) al[tid] = __expf(scores[b * T_DIM + tc * 64 + tid] - mx) * inv;
  __syncthreads();
  const __bf16* hp = hiddenBf + (size_t)b * T_DIM * H_DIM + (size_t)tc * 64 * H_DIM + tid * 4;
  float4 acc = make_float4(0.f, 0.f, 0.f, 0.f);
#pragma unroll 8
  for (int t = 0; t < 64; ++t) {
    float a = al[t];
    ushort4 u = *reinterpret_cast<const ushort4*>(hp + (size_t)t * H_DIM);
    acc.x += a * bf2f(u.x);
    acc.y += a * bf2f(u.y);
    acc.z += a * bf2f(u.z);
    acc.w += a * bf2f(u.w);
  }
  *reinterpret_cast<float4*>(r8 + (size_t)(b * 8 + tc) * H_DIM + tid * 4) = acc;
}

// ---- rp = (sum_tc parts) @ W_p^T + b_p ; xq = hidden[:,-1,:] @ W_x^T + b_x ----
// grid (H/64, B/IG, 2). NP = partial count (32 new path, 8 fallback), compile-time
// for full unroll. Partials re-read is L3-resident (<=8 MiB).
template <int NP>
__global__ void rowvec2_kernel(const float* __restrict__ parts,
                               const float* __restrict__ hidden,
                               const float* __restrict__ W_p, const float* __restrict__ b_p,
                               const float* __restrict__ W_x, const float* __restrict__ b_x,
                               float* __restrict__ rp, float* __restrict__ xq) {
  __shared__ __attribute__((aligned(16))) float sv[IG][H_DIM];
  const int h0 = blockIdx.x * 64;
  const int i0 = blockIdx.y * IG;
  const int which = blockIdx.z;
  const int tid = threadIdx.x;
  const float* W = which ? W_x : W_p;
  const float* bias = which ? b_x : b_p;
  float* dst = which ? xq : rp;
  if (which == 0) {
#pragma unroll
    for (int ii = 0; ii < IG; ++ii) {
      const float* src = parts + (size_t)(i0 + ii) * NP * H_DIM + tid * 4;
      float4 a = *reinterpret_cast<const float4*>(src);
#pragma unroll 8
      for (int tc = 1; tc < NP; ++tc) {
        float4 v = *reinterpret_cast<const float4*>(src + (size_t)tc * H_DIM);
        a.x += v.x; a.y += v.y; a.z += v.z; a.w += v.w;
      }
      *reinterpret_cast<float4*>(&sv[ii][tid * 4]) = a;
    }
  } else {
#pragma unroll
    for (int ii = 0; ii < IG; ++ii) {
      const float* src = hidden + (size_t)(i0 + ii) * T_DIM * H_DIM +
                         (size_t)(T_DIM - 1) * H_DIM + tid * 4;
      *reinterpret_cast<float4*>(&sv[ii][tid * 4]) = *reinterpret_cast<const float4*>(src);
    }
  }
  __syncthreads();
  const int hl = tid >> 2;        // output row within block: 0..63
  const int kq = tid & 3;         // 4 lanes split K, contiguous 64B per group
  const float* wr = W + (size_t)(h0 + hl) * H_DIM + kq * 4;
  float acc[IG] = {};
#pragma unroll 8
  for (int j = 0; j < 64; ++j) {
    float4 w4 = *reinterpret_cast<const float4*>(wr + j * 16);
#pragma unroll
    for (int ii = 0; ii < IG; ++ii) {
      float4 s4 = *reinterpret_cast<const float4*>(&sv[ii][kq * 4 + j * 16]);
      acc[ii] += w4.x * s4.x + w4.y * s4.y + w4.z * s4.z + w4.w * s4.w;
    }
  }
#pragma unroll
  for (int ii = 0; ii < IG; ++ii) {
    acc[ii] += __shfl_xor(acc[ii], 1, 4);
    acc[ii] += __shfl_xor(acc[ii], 2, 4);
  }
  if (kq == 0) {
    float bb = bias[h0 + hl];
#pragma unroll
    for (int ii = 0; ii < IG; ++ii)
      dst[(size_t)(i0 + ii) * H_DIM + h0 + hl] = acc[ii] + bb;
  }
}

// ---------------- out[i,j,h] = tanh(rp[i,h] + xq[j,h])  [B,B,H] quirk ----------------
__global__ void final_kernel(const float* __restrict__ rp, const float* __restrict__ xq,
                             float* __restrict__ out) {
  int idx = blockIdx.x * 256 + threadIdx.x;  // one float4 each
  int e = idx * 4;
  int i = e >> 16;
  int j = (e >> 10) & 63;
  int h = e & 1023;
  float4 a = *reinterpret_cast<const float4*>(&rp[i * H_DIM + h]);
  float4 b = *reinterpret_cast<const float4*>(&xq[j * H_DIM + h]);
  float4 o;
  o.x = tanh_fast(a.x + b.x);
  o.y = tanh_fast(a.y + b.y);
  o.z = tanh_fast(a.z + b.z);
  o.w = tanh_fast(a.w + b.w);
  *reinterpret_cast<float4*>(&out[e]) = o;
}

extern "C" void kernel_launch(void* const* d_in, const int* in_sizes, int n_in,
                              void* d_out, int out_size, void* d_ws, size_t ws_size,
                              hipStream_t stream) {
  const float* hidden = (const float*)d_in[0];
  // aspect (1), W_v (4), b_v (5), w_b (7) cancel under softmax -> unused
  const float* W_h = (const float*)d_in[2];
  const float* b_h = (const float*)d_in[3];
  const float* w_w = (const float*)d_in[6];  // use first H entries
  const float* W_p = (const float*)d_in[8];
  const float* b_p = (const float*)d_in[9];
  const float* W_x = (const float*)d_in[10];
  const float* b_x = (const float*)d_in[11];
  float* out = (float*)d_out;

  char* ws = (char*)d_ws;
  __bf16* hidBf = (__bf16*)ws;                  // 64 MB  [0, 67108864)
  __bf16* whBf = (__bf16*)(ws + 67108864);      // 2 MB   [67108864, 69206016)
  float* r8 = (float*)(ws + 67108864);          // 2 MB, ALIASES whBf (fallback path;
                                                // whBf dead after gemm)
  float* scores = (float*)(ws + 69206016);      // 128 KB [69206016, 69337088)
  float* rpB = (float*)(ws + 69337088);         // 256 KB
  float* xqB = (float*)(ws + 69599232);         // 256 KB (ends 69861376)
  float* r32 = (float*)(ws + 69861376);         // 8 MB   (ends 78249984)
  const bool big_ws = ws_size >= 78249984ULL;

  // 1) cvt hidden + cvt W_h + zero scores (one launch, 33824 blocks)
  prep_kernel<<<33824, 256, 0, stream>>>(hidden, hidBf, W_h, whBf, scores);

  // 2) fused GEMM -> scores (256x128 tiles, 1024 blocks, XCD-swizzled)
  gemm_scores_kernel<<<1024, 256, 0, stream>>>(hidBf, whBf, b_h, w_w, scores);

  // 3+4) softmax/weighted-sum partials, then rp/xq in one launch
  if (big_ws) {
    wsum32_kernel<<<2048, 256, 0, stream>>>(scores, hidBf, r32);
    rowvec2_kernel<32><<<dim3(H_DIM / 64, B_DIM / IG, 2), 256, 0, stream>>>(
        r32, hidden, W_p, b_p, W_x, b_x, rpB, xqB);
  } else {
    wsum_kernel<<<512, 256, 0, stream>>>(scores, hidBf, r8);
    rowvec2_kernel<8><<<dim3(H_DIM / 64, B_DIM / IG, 2), 256, 0, stream>>>(
        r8, hidden, W_p, b_p, W_x, b_x, rpB, xqB);
  }

  // 5) out[i,j,h] = tanh(rp[i,h] + xq[j,h])
  final_kernel<<<(B_DIM * B_DIM * H_DIM / 4) / 256, 256, 0, stream>>>(rpB, xqB, out);
}

// Round 6
// 354.226 us; speedup vs baseline: 2.9180x; 1.0123x over previous
//
#include <hip/hip_runtime.h>
#include <hip/hip_bf16.h>
#include <stdint.h>

// Problem dims (fixed by reference): B=64, T=512, H=1024, A=300
#define B_DIM 64
#define T_DIM 512
#define H_DIM 1024
#define K_DIM 1024
#define M_DIM (B_DIM * T_DIM)  // 32768 rows of the big GEMM
#define GM_BK 64
#define IG 4

typedef __bf16 bf16x8 __attribute__((ext_vector_type(8)));
typedef float f32x4 __attribute__((ext_vector_type(4)));

__device__ __forceinline__ float tanh_fast(float x) {
  float e = __expf(2.0f * x);
  return 1.0f - 2.0f / (e + 1.0f);
}

__device__ __forceinline__ float bf2f(unsigned short u) {
  return __uint_as_float(((unsigned int)u) << 16);
}

// async global->LDS, 16B per lane. LDS dest must be wave-uniform base + lane*16.
__device__ __forceinline__ void async_cp16(const void* gp, void* lp) {
  __builtin_amdgcn_global_load_lds(
      reinterpret_cast<const __attribute__((address_space(1))) uint32_t*>(
          reinterpret_cast<uintptr_t>(gp)),
      reinterpret_cast<__attribute__((address_space(3))) uint32_t*>(
          reinterpret_cast<uintptr_t>(lp)),
      16, 0, 0);
}

__device__ __forceinline__ void cvt4(const float4& v, uint2* dst) {
  union { __bf16 b[4]; uint2 u; } o;
  o.b[0] = (__bf16)v.x; o.b[1] = (__bf16)v.y; o.b[2] = (__bf16)v.z; o.b[3] = (__bf16)v.w;
  *dst = o.u;
}

// ---- prep: cvt hidden + cvt W_h. Grid-stride, 2048 blocks (G11). ----
#define STRIDE_NTHR (2048 * 256)
__global__ void prep_kernel(const float* __restrict__ hidden, __bf16* __restrict__ hidBf,
                            const float* __restrict__ Wh, __bf16* __restrict__ whBf) {
  const int gt = blockIdx.x * 256 + threadIdx.x;  // 524288 threads
  const float4* hs = reinterpret_cast<const float4*>(hidden);
  uint2* hd = reinterpret_cast<uint2*>(hidBf);
#pragma unroll 4
  for (int i = gt; i < 8388608; i += STRIDE_NTHR) {  // 16 iters exact
    cvt4(hs[i], &hd[i]);
  }
  const float4* wsrc = reinterpret_cast<const float4*>(Wh);
  uint2* wd = reinterpret_cast<uint2*>(whBf);
  if (gt < 262144) cvt4(wsrc[gt], &wd[gt]);  // W_h: 262144 float4
}

// ---------------- fused GEMM + tanh + dot(w_w) -> scoresP (m-half) ----
// Verified 256Mx128N structure, split into two m-halves of 512 blocks each
// (~43us) so rocprof top-5 can surface any other kernel >43us.
// R5 BUG FIXED: waves (wn=0, wn=1) cover the SAME m rows with different
// n-halves; a plain per-wave store raced and dropped half the contribution.
// Now: LDS wn-reduction (sBuf reuses lA, free after the K-loop's final
// syncthreads), then ONE coalesced non-atomic store per m. No atomics, no
// zero-init. XCD swizzle: m-tile = bid&63 (consecutive bids share n-panel).
__global__ __launch_bounds__(256, 2) void gemm_scores_kernel(
    const __bf16* __restrict__ A, const __bf16* __restrict__ Bm,
    const float* __restrict__ bh, const float* __restrict__ ww,
    float* __restrict__ scoresP, int m_base) {
  __shared__ __attribute__((aligned(16))) __bf16 lA[256 * GM_BK];
  __shared__ __attribute__((aligned(16))) __bf16 lB[128 * GM_BK];
  const int tid = threadIdx.x;
  const int bid = blockIdx.x;
  const int m0 = (bid & 63) * 256 + m_base;
  const int nIdx = bid >> 6;
  const int n0 = nIdx * 128;
  const int wv = tid >> 6;
  const int lane = tid & 63;
  const int wm = wv & 1, wn = wv >> 1;
  const int r16 = lane & 15, quad = lane >> 4;
  f32x4 acc[8][4] = {};
  const __bf16* gA[8]; __bf16* lAd[8];
#pragma unroll
  for (int j = 0; j < 8; ++j) {
    int c = j * 256 + tid;
    int row = c >> 3;
    int p = c & 7;
    int kc = p ^ ((row >> 1) & 7);
    gA[j] = A + (size_t)(m0 + row) * K_DIM + kc * 8;
    lAd[j] = &lA[c * 8];
  }
  const __bf16* gB[4]; __bf16* lBd[4];
#pragma unroll
  for (int j = 0; j < 4; ++j) {
    int c = j * 256 + tid;
    int row = c >> 3;
    int p = c & 7;
    int kc = p ^ ((row >> 1) & 7);
    gB[j] = Bm + (size_t)(n0 + row) * K_DIM + kc * 8;
    lBd[j] = &lB[c * 8];
  }
  const int sw = r16 >> 1;
  const __bf16* pa[2]; const __bf16* pb[2];
#pragma unroll
  for (int kk = 0; kk < 2; ++kk) {
    pa[kk] = &lA[(wm * 128 + r16) * GM_BK + ((kk * 4 + quad) ^ sw) * 8];
    pb[kk] = &lB[(wn * 64 + r16) * GM_BK + ((kk * 4 + quad) ^ sw) * 8];
  }
#pragma unroll
  for (int k0 = 0; k0 < K_DIM; k0 += GM_BK) {
#pragma unroll
    for (int j = 0; j < 8; ++j) async_cp16(gA[j] + k0, lAd[j]);
#pragma unroll
    for (int j = 0; j < 4; ++j) async_cp16(gB[j] + k0, lBd[j]);
    __syncthreads();
#pragma unroll
    for (int kk = 0; kk < 2; ++kk) {
      bf16x8 bfr[4];
#pragma unroll
      for (int ni = 0; ni < 4; ++ni)
        bfr[ni] = *reinterpret_cast<const bf16x8*>(pb[kk] + ni * 16 * GM_BK);
      bf16x8 af[8];
#pragma unroll
      for (int mi = 0; mi < 8; ++mi)
        af[mi] = *reinterpret_cast<const bf16x8*>(pa[kk] + mi * 16 * GM_BK);
#pragma unroll
      for (int mi = 0; mi < 8; ++mi)
#pragma unroll
        for (int ni = 0; ni < 4; ++ni)
          acc[mi][ni] = __builtin_amdgcn_mfma_f32_16x16x32_bf16(af[mi], bfr[ni], acc[mi][ni], 0, 0, 0);
    }
    __syncthreads();
  }
  // epilogue: C/D layout col=lane&15, row=quad*4+reg (m89-verified).
  // Last K-iter ended with __syncthreads -> lA reusable as the sBuf scratch.
  float* sBuf = reinterpret_cast<float*>(lA);  // [2][256] floats = 2 KB
  float bhv[4], wwv[4];
#pragma unroll
  for (int ni = 0; ni < 4; ++ni) {
    int n = n0 + wn * 64 + ni * 16 + r16;
    bhv[ni] = bh[n];
    wwv[ni] = ww[n];
  }
#pragma unroll
  for (int mi = 0; mi < 8; ++mi) {
#pragma unroll
    for (int rg = 0; rg < 4; ++rg) {
      float s = 0.f;
#pragma unroll
      for (int ni = 0; ni < 4; ++ni)
        s += tanh_fast(acc[mi][ni][rg] + bhv[ni]) * wwv[ni];
      s += __shfl_xor(s, 1, 16);
      s += __shfl_xor(s, 2, 16);
      s += __shfl_xor(s, 4, 16);
      s += __shfl_xor(s, 8, 16);
      if (r16 == 0) {
        int lm = wm * 128 + mi * 16 + quad * 4 + rg;  // local m: 0..255
        sBuf[wn * 256 + lm] = s;                      // unique (wn, lm) writer
      }
    }
  }
  __syncthreads();
  // wn-reduction + one coalesced store per m (unique across blocks: (nIdx, m))
  scoresP[nIdx * M_DIM + m0 + tid] = sBuf[tid] + sBuf[256 + tid];
}

// ------- wsum (R1-verified structure): softmax + weighted-sum partials, 512 blocks -------
// scores row = sum of 8 n-panel partials (16 KB of L2-resident reads per block).
__global__ void wsum_kernel(const float* __restrict__ scoresP,
                            const __bf16* __restrict__ hiddenBf,
                            float* __restrict__ r8) {
  __shared__ float sc[512];
  __shared__ float al[64];
  __shared__ float red[8];
  const int bid = blockIdx.x, tid = threadIdx.x;
  const int b = bid >> 3, tc = bid & 7;
  const int wv = tid >> 6, lane = tid & 63;
  float v0 = 0.f, v1 = 0.f;
#pragma unroll
  for (int p = 0; p < 8; ++p) {
    v0 += scoresP[p * M_DIM + b * T_DIM + tid];
    v1 += scoresP[p * M_DIM + b * T_DIM + 256 + tid];
  }
  sc[tid] = v0;
  sc[tid + 256] = v1;
  float mx = fmaxf(v0, v1);
#pragma unroll
  for (int off = 1; off < 64; off <<= 1) mx = fmaxf(mx, __shfl_xor(mx, off, 64));
  if (lane == 0) red[wv] = mx;
  __syncthreads();
  mx = fmaxf(fmaxf(red[0], red[1]), fmaxf(red[2], red[3]));
  float e0 = __expf(v0 - mx), e1 = __expf(v1 - mx);
  float s = e0 + e1;
#pragma unroll
  for (int off = 1; off < 64; off <<= 1) s += __shfl_xor(s, off, 64);
  if (lane == 0) red[4 + wv] = s;
  __syncthreads();
  float inv = 1.0f / (red[4] + red[5] + red[6] + red[7]);
  if (tid < 64) al[tid] = __expf(sc[tc * 64 + tid] - mx) * inv;
  __syncthreads();
  const __bf16* hp = hiddenBf + (size_t)b * T_DIM * H_DIM + (size_t)tc * 64 * H_DIM + tid * 4;
  float4 acc = make_float4(0.f, 0.f, 0.f, 0.f);
#pragma unroll 8
  for (int t = 0; t < 64; ++t) {
    float a = al[t];
    ushort4 u = *reinterpret_cast<const ushort4*>(hp + (size_t)t * H_DIM);
    acc.x += a * bf2f(u.x);
    acc.y += a * bf2f(u.y);
    acc.z += a * bf2f(u.z);
    acc.w += a * bf2f(u.w);
  }
  *reinterpret_cast<float4*>(r8 + (size_t)(b * 8 + tc) * H_DIM + tid * 4) = acc;
}

// ---- rp = (sum_tc r8) @ W_p^T + b_p ; xq = hidden[:,-1,:] @ W_x^T + b_x ----
// grid (H/64, B/IG, 2). R1-verified (344us run).
__global__ void rowvec2_kernel(const float* __restrict__ r8,
                               const float* __restrict__ hidden,
                               const float* __restrict__ W_p, const float* __restrict__ b_p,
                               const float* __restrict__ W_x, const float* __restrict__ b_x,
                               float* __restrict__ rp, float* __restrict__ xq) {
  __shared__ __attribute__((aligned(16))) float sv[IG][H_DIM];
  const int h0 = blockIdx.x * 64;
  const int i0 = blockIdx.y * IG;
  const int which = blockIdx.z;
  const int tid = threadIdx.x;
  const float* W = which ? W_x : W_p;
  const float* bias = which ? b_x : b_p;
  float* dst = which ? xq : rp;
  if (which == 0) {
#pragma unroll
    for (int ii = 0; ii < IG; ++ii) {
      const float* src = r8 + (size_t)(i0 + ii) * 8 * H_DIM + tid * 4;
      float4 a = *reinterpret_cast<const float4*>(src);
#pragma unroll
      for (int tc = 1; tc < 8; ++tc) {
        float4 v = *reinterpret_cast<const float4*>(src + (size_t)tc * H_DIM);
        a.x += v.x; a.y += v.y; a.z += v.z; a.w += v.w;
      }
      *reinterpret_cast<float4*>(&sv[ii][tid * 4]) = a;
    }
  } else {
#pragma unroll
    for (int ii = 0; ii < IG; ++ii) {
      const float* src = hidden + (size_t)(i0 + ii) * T_DIM * H_DIM +
                         (size_t)(T_DIM - 1) * H_DIM + tid * 4;
      *reinterpret_cast<float4*>(&sv[ii][tid * 4]) = *reinterpret_cast<const float4*>(src);
    }
  }
  __syncthreads();
  const int hl = tid >> 2;        // output row within block: 0..63
  const int kq = tid & 3;         // 4 lanes split K, contiguous 64B per group
  const float* wr = W + (size_t)(h0 + hl) * H_DIM + kq * 4;
  float acc[IG] = {};
#pragma unroll 8
  for (int j = 0; j < 64; ++j) {
    float4 w4 = *reinterpret_cast<const float4*>(wr + j * 16);
#pragma unroll
    for (int ii = 0; ii < IG; ++ii) {
      float4 s4 = *reinterpret_cast<const float4*>(&sv[ii][kq * 4 + j * 16]);
      acc[ii] += w4.x * s4.x + w4.y * s4.y + w4.z * s4.z + w4.w * s4.w;
    }
  }
#pragma unroll
  for (int ii = 0; ii < IG; ++ii) {
    acc[ii] += __shfl_xor(acc[ii], 1, 4);
    acc[ii] += __shfl_xor(acc[ii], 2, 4);
  }
  if (kq == 0) {
    float bb = bias[h0 + hl];
#pragma unroll
    for (int ii = 0; ii < IG; ++ii)
      dst[(size_t)(i0 + ii) * H_DIM + h0 + hl] = acc[ii] + bb;
  }
}

// ------- out[i,j,h] = tanh(rp[i,h] + xq[j,h])  [B,B,H] quirk. Grid-stride (G11). -------
__global__ void final_kernel(const float* __restrict__ rp, const float* __restrict__ xq,
                             float* __restrict__ out) {
  const int gt = blockIdx.x * 256 + threadIdx.x;
#pragma unroll
  for (int idx = gt; idx < 1048576; idx += STRIDE_NTHR) {  // 2 iters exact
    int e = idx * 4;
    int i = e >> 16;
    int j = (e >> 10) & 63;
    int h = e & 1023;
    float4 a = *reinterpret_cast<const float4*>(&rp[i * H_DIM + h]);
    float4 b = *reinterpret_cast<const float4*>(&xq[j * H_DIM + h]);
    float4 o;
    o.x = tanh_fast(a.x + b.x);
    o.y = tanh_fast(a.y + b.y);
    o.z = tanh_fast(a.z + b.z);
    o.w = tanh_fast(a.w + b.w);
    *reinterpret_cast<float4*>(&out[e]) = o;
  }
}

extern "C" void kernel_launch(void* const* d_in, const int* in_sizes, int n_in,
                              void* d_out, int out_size, void* d_ws, size_t ws_size,
                              hipStream_t stream) {
  const float* hidden = (const float*)d_in[0];
  // aspect (1), W_v (4), b_v (5), w_b (7) cancel under softmax -> unused
  const float* W_h = (const float*)d_in[2];
  const float* b_h = (const float*)d_in[3];
  const float* w_w = (const float*)d_in[6];  // use first H entries
  const float* W_p = (const float*)d_in[8];
  const float* b_p = (const float*)d_in[9];
  const float* W_x = (const float*)d_in[10];
  const float* b_x = (const float*)d_in[11];
  float* out = (float*)d_out;

  // Workspace plan (peak 70,254,592 B = R0-proven size). Liveness:
  //   hidBf  [0, 64M)            written prep, read gemm+wsum, DEAD after wsum
  //   whBf   [64M, 66M)          written prep, read gemm, DEAD after gemm
  //   r8     aliases whBf        written wsum, read rowvec2
  //   scoresP[66M, 67M)          written gemm, read wsum
  //   rpB/xqB alias hidBf head   written rowvec2, read final (hidBf dead;
  //                              re-written fresh by prep next iteration)
  char* ws = (char*)d_ws;
  __bf16* hidBf = (__bf16*)ws;                  // 64 MB  [0, 67108864)
  __bf16* whBf = (__bf16*)(ws + 67108864);      // 2 MB   [67108864, 69206016)
  float* r8 = (float*)(ws + 67108864);          // 2 MB, ALIASES whBf
  float* scoresP = (float*)(ws + 69206016);     // 1 MB   [69206016, 70254592)
  float* rpB = (float*)ws;                      // 256 KB, ALIASES hidBf head
  float* xqB = (float*)(ws + 262144);           // 256 KB, ALIASES hidBf

  // 1) cvt hidden + cvt W_h (grid-stride, 2048 blocks)
  prep_kernel<<<2048, 256, 0, stream>>>(hidden, hidBf, W_h, whBf);

  // 2) fused GEMM -> scoresP, two m-halves (512 blocks each; LDS-reduced,
  //    coalesced non-atomic partial stores)
  gemm_scores_kernel<<<512, 256, 0, stream>>>(hidBf, whBf, b_h, w_w, scoresP, 0);
  gemm_scores_kernel<<<512, 256, 0, stream>>>(hidBf, whBf, b_h, w_w, scoresP, 16384);

  // 3) softmax (sums 8 partials) + weighted-sum partials (512 blocks)
  wsum_kernel<<<512, 256, 0, stream>>>(scoresP, hidBf, r8);

  // 4) rp and xq in one launch
  rowvec2_kernel<<<dim3(H_DIM / 64, B_DIM / IG, 2), 256, 0, stream>>>(
      r8, hidden, W_p, b_p, W_x, b_x, rpB, xqB);

  // 5) out[i,j,h] = tanh(rp[i,h] + xq[j,h]) (grid-stride, 2048 blocks)
  final_kernel<<<2048, 256, 0, stream>>>(rpB, xqB, out);
}